// Round 1
// baseline (202.112 us; speedup 1.0000x reference)
//
#include <hip/hip_runtime.h>

// EquiConv fused MFMA kernel for MI355X (gfx950).
// Strategy: all einsums are (edge x K) @ (K x N) GEMMs where the A matrix is an
// on-the-fly outer product of per-edge vectors. Weights are pre-packed (prep
// kernel) into bf16 B-fragment order with normalization constants folded in.
// Main kernel: 4 waves x 16 edges per block, mfma_f32_16x16x32_bf16,
// A-frag layout A[m=lane&15][k=(lane>>4)*8+j] (learn_hip m120, verified),
// C/D layout col=lane&15, row=(lane>>4)*4+reg (m89, verified).

#define E_TOT 20000

typedef __attribute__((ext_vector_type(8))) short short8;
typedef __attribute__((ext_vector_type(4))) float f32x4;
typedef __attribute__((ext_vector_type(2))) __bf16 bf16x2;

// ws layout offsets (ushort units); packed index = ((chunk*NT + t)*64 + lane)*8 + j
#define OFF_SS 0        // K=4096 NT=6  -> 393216
#define OFF_VV 393216   // K=1024 NT=6  ->  98304
#define OFF_SV 491520   // K=2048 NT=2  ->  65536
#define OFF_VS 557056   // K=2048 NT=2  ->  65536
#define OFF_F1 622592   // K=128  NT=4  ->   8192
#define OFF_F2 630784   // K=64   NT=4  ->   4096
#define OFF_F3 634880   // K=64   NT=6  ->   6144
#define N_TOTAL 641024  // *2B = 1.25 MB of d_ws

__device__ __forceinline__ unsigned short f2b(float f){
  return __builtin_bit_cast(unsigned short, (__bf16)f);
}
__device__ __forceinline__ unsigned f2b2(float lo, float hi){
  bf16x2 t; t[0] = (__bf16)lo; t[1] = (__bf16)hi;
  return __builtin_bit_cast(unsigned, t);
}
__device__ __forceinline__ float b2f(unsigned short h){
  return __uint_as_float(((unsigned)h) << 16);
}
__device__ __forceinline__ f32x4 mfma16(short8 a, short8 b, f32x4 c){
  return __builtin_amdgcn_mfma_f32_16x16x32_bf16(a, b, c, 0, 0, 0);
}
union U8 { short8 v; unsigned u[4]; };
__device__ __forceinline__ void up8(uint4 q, float* x){
  x[0]=__uint_as_float(q.x<<16); x[1]=__uint_as_float(q.x&0xffff0000u);
  x[2]=__uint_as_float(q.y<<16); x[3]=__uint_as_float(q.y&0xffff0000u);
  x[4]=__uint_as_float(q.z<<16); x[5]=__uint_as_float(q.z&0xffff0000u);
  x[6]=__uint_as_float(q.w<<16); x[7]=__uint_as_float(q.w&0xffff0000u);
}
__device__ __forceinline__ float silu_f(float x){ return x/(1.f+__expf(-x)); }
__device__ __forceinline__ float sigm_f(float x){ return 1.f/(1.f+__expf(-x)); }

#define PACK8(a, s, x) \
  a.u[0]=f2b2((s)*(x)[0],(s)*(x)[1]); a.u[1]=f2b2((s)*(x)[2],(s)*(x)[3]); \
  a.u[2]=f2b2((s)*(x)[4],(s)*(x)[5]); a.u[3]=f2b2((s)*(x)[6],(s)*(x)[7]);

// ---------------- prep: repack weights into bf16 fragment order ----------------
__global__ void prep_weights(const float* __restrict__ ss_s, const float* __restrict__ vv_s,
                             const float* __restrict__ ss_g, const float* __restrict__ vv_g,
                             const float* __restrict__ sv,   const float* __restrict__ vs,
                             const float* __restrict__ w1,   const float* __restrict__ w2,
                             const float* __restrict__ w3,   unsigned short* __restrict__ wsb)
{
  int idx = blockIdx.x * 256 + threadIdx.x;
  if (idx >= N_TOTAL) return;
  const float A_SC  = 0.013975424859373686f;                       // 1/sqrt(S*S+V*V)
  const float A_VV  = (float)(0.013975424859373686 * 0.5773502691896258);
  const float A_VEC = 0.015625f;                                   // 1/sqrt(2*S*V)
  int q, NT;
  if      (idx < OFF_VV){ q = idx;          NT = 6; }
  else if (idx < OFF_SV){ q = idx - OFF_VV; NT = 6; }
  else if (idx < OFF_VS){ q = idx - OFF_SV; NT = 2; }
  else if (idx < OFF_F1){ q = idx - OFF_VS; NT = 2; }
  else if (idx < OFF_F2){ q = idx - OFF_F1; NT = 4; }
  else if (idx < OFF_F3){ q = idx - OFF_F2; NT = 4; }
  else                  { q = idx - OFF_F3; NT = 6; }
  int j = q & 7, lane = (q >> 3) & 63;
  int t = (q >> 9) % NT, c = q / (NT << 9);
  int k = c*32 + ((lane >> 4) << 3) + j;   // K index (B frag: k = quad*8+j)
  int n = (t << 4) + (lane & 15);          // N index (B frag: n = lane&15)
  float v;
  if      (idx < OFF_VV) v = A_SC  * (n < 64 ? ss_s[k*64+n] : ss_g[k*32+(n-64)]); // k=u*64+v
  else if (idx < OFF_SV) v = A_VV  * (n < 64 ? vv_s[k*64+n] : vv_g[k*32+(n-64)]); // k=u*32+v
  else if (idx < OFF_VS) v = A_VEC * sv[k*32+n];                                  // k=u*32+v
  else if (idx < OFF_F1) v = A_VEC * vs[k*32+n];                                  // k=u*64+v (u in V, v in S)
  else if (idx < OFF_F2) v = w1[k*64+n];
  else if (idx < OFF_F3) v = w2[k*64+n];
  else                   v = w3[k*96+n];
  wsb[idx] = f2b(v);
}

// ---------------- main fused kernel ----------------
__global__ __launch_bounds__(256, 2)
void equiconv_main(const float* __restrict__ fea1,
                   const float* __restrict__ fea2,
                   const float* __restrict__ few,
                   const float* __restrict__ fb1,
                   const float* __restrict__ fb2,
                   const float* __restrict__ fb3,
                   const unsigned short* __restrict__ wsb,
                   float* __restrict__ out)
{
  // padded strides: keep b128 reads 16B-aligned and bank conflicts <= 2-way (free)
  __shared__ unsigned short ls_x1s[64][66];   // bf16, scalar reads
  __shared__ unsigned short ls_x1v[64][98];   // bf16 [e][u*3+i], scalar reads
  __shared__ float          ls_x2s[64][68];   // f32, vector reads
  __shared__ unsigned short ls_x2v[3][64][40];// bf16 [i][e][v], vector reads
  __shared__ unsigned short ls_h[4][16][72];  // per-wave FC activation buffer

  const int ebase = blockIdx.x << 6;

  // stage 64 edges of fea_in1 / fea_in2 into LDS (bf16 except x2s)
  for (int it = threadIdx.x; it < 2560; it += 256){
    int row = it / 40, seg = it - row*40;
    int src = ebase + row; if (src > E_TOT-1) src = E_TOT-1;
    float4 v1 = *(const float4*)(fea1 + (size_t)src*160 + seg*4);
    float4 v2 = *(const float4*)(fea2 + (size_t)src*160 + seg*4);
    const float* p1 = (const float*)&v1;
    const float* p2 = (const float*)&v2;
    int c0 = seg*4;
    #pragma unroll
    for (int jj=0;jj<4;jj++){
      int col = c0 + jj;
      if (col < 64){
        ls_x1s[row][col] = f2b(p1[jj]);
        ls_x2s[row][col] = p2[jj];
      } else {
        int cv = col - 64;
        ls_x1v[row][cv] = f2b(p1[jj]);
        ls_x2v[cv%3][row][cv/3] = f2b(p2[jj]);
      }
    }
  }
  __syncthreads();

  const int lane = threadIdx.x & 63;
  const int wv   = threadIdx.x >> 6;
  const int ln   = lane & 15;
  const int quad = lane >> 4;
  const int erow = (wv << 4) + ln;   // this lane's A-row edge (local)
  const int q8   = quad << 3;

  // hoisted per-lane x2 fragments (k = quad*8+j slices), loop-invariant
  float xe[8], xo[8], y0[8], y1[8], y2[8];
  {
    float4 a0 = *(const float4*)&ls_x2s[erow][q8];
    float4 a1 = *(const float4*)&ls_x2s[erow][q8+4];
    float4 b0 = *(const float4*)&ls_x2s[erow][32+q8];
    float4 b1 = *(const float4*)&ls_x2s[erow][36+q8];
    xe[0]=a0.x; xe[1]=a0.y; xe[2]=a0.z; xe[3]=a0.w;
    xe[4]=a1.x; xe[5]=a1.y; xe[6]=a1.z; xe[7]=a1.w;
    xo[0]=b0.x; xo[1]=b0.y; xo[2]=b0.z; xo[3]=b0.w;
    xo[4]=b1.x; xo[5]=b1.y; xo[6]=b1.z; xo[7]=b1.w;
    up8(*(const uint4*)&ls_x2v[0][erow][q8], y0);
    up8(*(const uint4*)&ls_x2v[1][erow][q8], y1);
    up8(*(const uint4*)&ls_x2v[2][erow][q8], y2);
  }

  const f32x4 z4 = {0.f,0.f,0.f,0.f};
  f32x4 accS[6] = {z4,z4,z4,z4,z4,z4};   // sc (tiles 0..3) + g (tiles 4,5)

  // ---- SS: sc/g += x1s (x) x2s . W_ss   (K=4096, two 32-chunks per u) ----
  {
    const short8* B = (const short8*)(wsb + OFF_SS);
    #pragma unroll 2
    for (int u=0; u<64; u++){
      float s = b2f(ls_x1s[erow][u]);
      U8 a; PACK8(a, s, xe);
      const short8* bp = B + (u*12)*64 + lane;
      #pragma unroll
      for (int t=0;t<6;t++) accS[t] = mfma16(a.v, bp[t*64], accS[t]);
      PACK8(a, s, xo);
      bp += 6*64;
      #pragma unroll
      for (int t=0;t<6;t++) accS[t] = mfma16(a.v, bp[t*64], accS[t]);
    }
  }
  // ---- VV: sc/g += (x1v . x2v) . W_vv   (K=1024) ----
  {
    const short8* B = (const short8*)(wsb + OFF_VV);
    #pragma unroll 2
    for (int u=0; u<32; u++){
      float s0 = b2f(ls_x1v[erow][u*3+0]);
      float s1 = b2f(ls_x1v[erow][u*3+1]);
      float s2 = b2f(ls_x1v[erow][u*3+2]);
      float p[8];
      #pragma unroll
      for (int j=0;j<8;j++) p[j] = s0*y0[j] + s1*y1[j] + s2*y2[j];
      U8 a;
      a.u[0]=f2b2(p[0],p[1]); a.u[1]=f2b2(p[2],p[3]);
      a.u[2]=f2b2(p[4],p[5]); a.u[3]=f2b2(p[6],p[7]);
      const short8* bp = B + (u*6)*64 + lane;
      #pragma unroll
      for (int t=0;t<6;t++) accS[t] = mfma16(a.v, bp[t*64], accS[t]);
    }
  }
  // ---- SV + VS -> vec accumulators (3 component-GEMMs each, shared B) ----
  f32x4 accV[3][2] = {{z4,z4},{z4,z4},{z4,z4}};
  {
    const short8* B = (const short8*)(wsb + OFF_SV);  // k = u*32+v, u in S
    #pragma unroll 2
    for (int u=0; u<64; u++){
      float s = b2f(ls_x1s[erow][u]);
      U8 a0, a1, a2;
      PACK8(a0, s, y0); PACK8(a1, s, y1); PACK8(a2, s, y2);
      const short8* bp = B + (u*2)*64 + lane;
      short8 bb0 = bp[0], bb1 = bp[64];
      accV[0][0]=mfma16(a0.v,bb0,accV[0][0]); accV[0][1]=mfma16(a0.v,bb1,accV[0][1]);
      accV[1][0]=mfma16(a1.v,bb0,accV[1][0]); accV[1][1]=mfma16(a1.v,bb1,accV[1][1]);
      accV[2][0]=mfma16(a2.v,bb0,accV[2][0]); accV[2][1]=mfma16(a2.v,bb1,accV[2][1]);
    }
  }
  {
    const short8* B = (const short8*)(wsb + OFF_VS);  // k = u*64+v, u in V
    #pragma unroll 2
    for (int u=0; u<32; u++){
      float s0 = b2f(ls_x1v[erow][u*3+0]);
      float s1 = b2f(ls_x1v[erow][u*3+1]);
      float s2 = b2f(ls_x1v[erow][u*3+2]);
      const short8* bp = B + (u*4)*64 + lane;
      U8 a0, a1, a2;
      PACK8(a0, s0, xe); PACK8(a1, s1, xe); PACK8(a2, s2, xe);
      short8 bb0 = bp[0], bb1 = bp[64];
      accV[0][0]=mfma16(a0.v,bb0,accV[0][0]); accV[0][1]=mfma16(a0.v,bb1,accV[0][1]);
      accV[1][0]=mfma16(a1.v,bb0,accV[1][0]); accV[1][1]=mfma16(a1.v,bb1,accV[1][1]);
      accV[2][0]=mfma16(a2.v,bb0,accV[2][0]); accV[2][1]=mfma16(a2.v,bb1,accV[2][1]);
      PACK8(a0, s0, xo); PACK8(a1, s1, xo); PACK8(a2, s2, xo);
      short8 bb2 = bp[128], bb3 = bp[192];
      accV[0][0]=mfma16(a0.v,bb2,accV[0][0]); accV[0][1]=mfma16(a0.v,bb3,accV[0][1]);
      accV[1][0]=mfma16(a1.v,bb2,accV[1][0]); accV[1][1]=mfma16(a1.v,bb3,accV[1][1]);
      accV[2][0]=mfma16(a2.v,bb2,accV[2][0]); accV[2][1]=mfma16(a2.v,bb3,accV[2][1]);
    }
  }
  // ---- FC1: h1 = silu(fw @ W1 + b1) ----
  f32x4 accF[4] = {z4,z4,z4,z4};
  {
    int src = ebase + erow; if (src > E_TOT-1) src = E_TOT-1;
    const float* fwp = few + (size_t)src*128;
    const short8* B = (const short8*)(wsb + OFF_F1);
    #pragma unroll
    for (int c=0;c<4;c++){
      float4 fa = *(const float4*)(fwp + c*32 + q8);
      float4 fbv = *(const float4*)(fwp + c*32 + q8 + 4);
      U8 a;
      a.u[0]=f2b2(fa.x,fa.y);   a.u[1]=f2b2(fa.z,fa.w);
      a.u[2]=f2b2(fbv.x,fbv.y); a.u[3]=f2b2(fbv.z,fbv.w);
      const short8* bp = B + (c*4)*64 + lane;
      #pragma unroll
      for (int t=0;t<4;t++) accF[t] = mfma16(a.v, bp[t*64], accF[t]);
    }
  }
  #pragma unroll
  for (int t=0;t<4;t++){
    float bb = fb1[(t<<4)+ln];
    #pragma unroll
    for (int r=0;r<4;r++)
      ls_h[wv][(quad<<2)+r][(t<<4)+ln] = f2b(silu_f(accF[t][r] + bb));
  }
  // ---- FC2 ----
  f32x4 acc2[4] = {z4,z4,z4,z4};
  {
    const short8* B = (const short8*)(wsb + OFF_F2);
    #pragma unroll
    for (int c=0;c<2;c++){
      uint4 hq = *(const uint4*)&ls_h[wv][ln][c*32 + q8];
      U8 a; a.u[0]=hq.x; a.u[1]=hq.y; a.u[2]=hq.z; a.u[3]=hq.w;
      const short8* bp = B + (c*4)*64 + lane;
      #pragma unroll
      for (int t=0;t<4;t++) acc2[t] = mfma16(a.v, bp[t*64], acc2[t]);
    }
  }
  #pragma unroll
  for (int t=0;t<4;t++){
    float bb = fb2[(t<<4)+ln];
    #pragma unroll
    for (int r=0;r<4;r++)
      ls_h[wv][(quad<<2)+r][(t<<4)+ln] = f2b(silu_f(acc2[t][r] + bb));
  }
  // ---- FC3: w = h2 @ W3 + b3 ----
  f32x4 acc3[6] = {z4,z4,z4,z4,z4,z4};
  {
    const short8* B = (const short8*)(wsb + OFF_F3);
    #pragma unroll
    for (int c=0;c<2;c++){
      uint4 hq = *(const uint4*)&ls_h[wv][ln][c*32 + q8];
      U8 a; a.u[0]=hq.x; a.u[1]=hq.y; a.u[2]=hq.z; a.u[3]=hq.w;
      const short8* bp = B + (c*6)*64 + lane;
      #pragma unroll
      for (int t=0;t<6;t++) acc3[t] = mfma16(a.v, bp[t*64], acc3[t]);
    }
  }
  // ---- epilogue: silu/sigmoid gating, FC3 scaling, store ----
  #pragma unroll
  for (int r=0;r<4;r++){
    int eg = ebase + (wv<<4) + (quad<<2) + r;    // C-layout row = quad*4+r
    if (eg < E_TOT){
      float* op = out + (size_t)eg*160;
      #pragma unroll
      for (int t=0;t<4;t++){
        float w3 = acc3[t][r] + fb3[(t<<4)+ln];
        op[(t<<4)+ln] = silu_f(accS[t][r]) * w3;
      }
      #pragma unroll
      for (int tp=0;tp<2;tp++){
        int wcol = (tp<<4) + ln;
        float f = sigm_f(accS[4+tp][r]) * (acc3[4+tp][r] + fb3[64+wcol]);
        op[64 + wcol*3 + 0] = accV[0][tp][r] * f;
        op[64 + wcol*3 + 1] = accV[1][tp][r] * f;
        op[64 + wcol*3 + 2] = accV[2][tp][r] * f;
      }
    }
  }
}

extern "C" void kernel_launch(void* const* d_in, const int* in_sizes, int n_in,
                              void* d_out, int out_size, void* d_ws, size_t ws_size,
                              hipStream_t stream) {
  (void)in_sizes; (void)n_in; (void)out_size; (void)ws_size;
  const float* fea1 = (const float*)d_in[0];
  const float* fea2 = (const float*)d_in[1];
  const float* few  = (const float*)d_in[2];
  unsigned short* wsb = (unsigned short*)d_ws;

  prep_weights<<<(N_TOTAL + 255)/256, 256, 0, stream>>>(
      (const float*)d_in[3], (const float*)d_in[4],
      (const float*)d_in[5], (const float*)d_in[6],
      (const float*)d_in[7], (const float*)d_in[8],
      (const float*)d_in[9], (const float*)d_in[11], (const float*)d_in[13],
      wsb);

  equiconv_main<<<(E_TOT + 63)/64, 256, 0, stream>>>(
      fea1, fea2, few,
      (const float*)d_in[10], (const float*)d_in[12], (const float*)d_in[14],
      (const unsigned short*)wsb, (float*)d_out);
}